// Round 1
// 150.244 us; speedup vs baseline: 1.0500x; 1.0500x over previous
//
#include <hip/hip_runtime.h>

// Network_49873160241834: fused LIF scan (B=256,F=10,C=3,T=8192) + conv(c) + linear(f).
//
// Speculative time-chunking (unchanged from prior version): 16 chunks of 512 steps,
// 256-step warmup; LIF resets v to exactly 0 on spikes so warmed-up state is bit-exact.
// Each 64-thread block (= 1 wave, no barriers needed) simulates TWO chunks
// (half 0 = chunk 2cb, half 1 = chunk 2cb+1) -> grid (B, 8) = 2048 blocks.
//
// NEW in this round: the register double-buffer of x was being defeated by the
// compiler (VGPR=44 < the 64 regs the buffers needed -> loads sunk next to uses ->
// ~200-400cyc vmcnt stall every 4 steps; VALUBusy 36%). Replaced with LDS staging:
//  - x window (32 steps) staged in LDS, shared across the 3 c-lanes per (b,f) row:
//    20 rows x 32 floats = 2.5 KB/window, double-buffered.
//  - T14 async split: issue 3 global_load_dwordx4 for window w+1 at loop top,
//    sim window w from LDS (~700 cyc of cover), then ds_write the regs. Compiler
//    can't sink the loads (ds_write data dep) nor hoist next window's ds_reads
//    (may-alias) -> issue->wait distance is a full window by construction.
//  - float4-granularity XOR swizzle (q ^ (row&7)) on BOTH ds_write and ds_read
//    (linear layout would put all 20 rows in one bank-quad).
//  - per-step x via ds_read_b128 (1 per 4 steps), 2-group software prefetch.
//
// Spike capture + LUT epilogue unchanged: per step __ballot -> wave-uniform 64-bit
// mask; lane (o,tt) latches it at step tt; per-window 6x(bfe+LDS-LUT+add).
//
// EXACTNESS: v-update uses separately-rounded f32 ops (no FMA contraction) to match
// the f32 reference bit-exactly; chunk-0 staging pointers rewind 256 floats at the
// warmup->main transition to reproduce the original overlapping stream.

#define T_LEN 8192
#define NF 10
#define NSEQ 30
#define CHUNK 512
#define WARM 256
#define NCHUNKS 16          // T_LEN / CHUNK
#define NWIN 24             // (WARM + CHUNK) / 32 windows per chunk
#define WWIN 8              // warmup windows
#define NROW 20             // staged rows: 2 halves x 10 f
#define BUF4 (NROW * 8)     // float4s per window buffer (160)

__device__ __forceinline__ float lif_step(float xx, float v, float k, float vt, bool& s) {
  float d  = __fsub_rn(xx, v);   // rounded f32 sub
  float p  = __fmul_rn(k, d);    // rounded f32 mul (NOT fused)
  float vn = __fadd_rn(v, p);    // rounded f32 add
  s = vn > vt;                   // == (fl(vn - vt) > 0) in IEEE f32
  return s ? 0.0f : vn;          // exact reset to +0
}

__device__ __forceinline__ float lut_sum(unsigned m, const float* lut, int o, float bias) {
  float acc = bias;
#pragma unroll
  for (int g = 0; g < 6; ++g) {
    unsigned val = (m >> (5 * g)) & 31u;
    acc += lut[(g * 2 + o) * 32 + val];
  }
  return acc;
}

__global__ __launch_bounds__(64, 2) void lif_chunked(
    const float* __restrict__ x,      // (B, F, T)
    const float* __restrict__ tau,    // (3)
    const float* __restrict__ vth,    // (3)
    const float* __restrict__ convw,  // (3)
    const float* __restrict__ convb,  // (1)
    const float* __restrict__ linw,   // (2,10)
    const float* __restrict__ linb,   // (2)
    float* __restrict__ out)          // (B, 2, T)
{
  const int b    = blockIdx.x;
  const int cb   = blockIdx.y;       // 0..7, handles chunks 2cb, 2cb+1
  const int lane = threadIdx.x;
  const int half = lane >> 5;
  const int j    = lane & 31;
  const bool active = j < NSEQ;
  const int c = active ? j / NF : 0;
  const int f = active ? j % NF : 0;

  // LUT[g][o][val] = sum over set bits p of val of convw[(5g+p)/10]*linw[o,(5g+p)%10]
  __shared__ float lut[384];
  __shared__ float4 xbuf[2][BUF4];   // double-buffered x window, XOR-swizzled
#pragma unroll
  for (int e = 0; e < 6; ++e) {
    int id = lane + 64 * e;
    int g = id >> 6, rem = id & 63, oo = rem >> 5, val = rem & 31;
    float sacc = 0.0f;
#pragma unroll
    for (int p = 0; p < 5; ++p) {
      if (val & (1 << p)) {
        int jj = 5 * g + p;
        sacc += convw[jj / NF] * linw[oo * NF + (jj % NF)];
      }
    }
    lut[id] = sacc;
  }
  __syncthreads();

  const float k  = __fmul_rn(0.001f, tau[c]);
  const float vt = active ? vth[c] : 3.0e38f;   // inactive lanes never spike
  const int chunk = cb * 2 + half;              // this lane's simulated chunk

  // sim-side LDS read base: row = half*10 + f, swizzle key = row & 7
  const int srow = half * NF + f;
  const int sw   = srow & 7;
  const float4* rbase = &xbuf[0][srow * 8];

  // staging assignment: 160 (row,q) float4 slots; slots 0..63 -> lanes (i=0),
  // 64..127 (i=1), 128..159 mirrored on both half-waves (i=2).
  const float4* gp[3];   // global src, advances 8 float4/window
  float4*       lp[3];   // LDS dst in xbuf[0] (+BUF4 for buf 1), swizzled
  int           adj[3];  // chunk-0 rewind (float4 units) at warmup->main
#pragma unroll
  for (int i = 0; i < 3; ++i) {
    int id  = (i == 0) ? lane : (i == 1) ? (lane + 64) : ((lane & 31) + 128);
    int row = id >> 3;
    int q   = id & 7;
    int h   = row / NF;
    int fr  = row % NF;
    int ch  = 2 * cb + h;
    int ts  = (ch == 0) ? 0 : ch * CHUNK - WARM;
    gp[i]  = (const float4*)(x + ((size_t)b * NF + fr) * (size_t)T_LEN + ts) + q;
    lp[i]  = &xbuf[0][row * 8 + (q ^ (row & 7))];
    adj[i] = (ch == 0) ? -(WARM / 4) : 0;
  }

  // epilogue role: lane = (o, tt)
  const int o  = half;
  const int tt = j;
  float wsum = 0.0f;
#pragma unroll
  for (int f2 = 0; f2 < NF; ++f2) wsum += linw[o * NF + f2];
  const float bias = linb[o] + convb[0] * wsum;

  const int tA = 2 * cb * CHUNK;             // half-0 chunk base time (block-uniform)
  float* outA = out + ((size_t)b * 2 + o) * T_LEN + tA;
  float* outB = outA + CHUNK;                // half-1 chunk base

  // ---- prologue: stage window 0 into buf 0
  {
    float4 s0 = gp[0][0], s1 = gp[1][0], s2 = gp[2][0];
    *lp[0] = s0; *lp[1] = s1; *lp[2] = s2;
    gp[0] += 8; gp[1] += 8; gp[2] += 8;
  }

  float v = 0.0f;

#pragma unroll 1
  for (int w = 0; w < NWIN; ++w) {
    const bool haveNext = (w + 1 < NWIN);
    float4 s0, s1, s2;
    if (haveNext) {
      if (w + 1 == WWIN) {   // chunk-0 rows rewind to t=0 for the main phase
        gp[0] += adj[0]; gp[1] += adj[1]; gp[2] += adj[2];
      }
      s0 = gp[0][0]; s1 = gp[1][0]; s2 = gp[2][0];   // issue early (T14)
      gp[0] += 8; gp[1] += 8; gp[2] += 8;
    }

    const float4* rp = rbase + (w & 1) * BUF4;

    if (w < WWIN) {
      // ---- warmup window: 32 steps, no capture
      float4 x0 = rp[0 ^ sw];
      float4 x1 = rp[1 ^ sw];
#pragma unroll
      for (int q = 0; q < 8; ++q) {
        float4 xn = x1;
        if (q + 2 < 8) xn = rp[(q + 2) ^ sw];
        bool s;
        v = lif_step(x0.x, v, k, vt, s);
        v = lif_step(x0.y, v, k, vt, s);
        v = lif_step(x0.z, v, k, vt, s);
        v = lif_step(x0.w, v, k, vt, s);
        x0 = x1; x1 = xn;
      }
      if (w == WWIN - 1) v = (chunk == 0) ? 0.0f : v;  // chunk 0's true init state
    } else {
      // ---- main window: 32 steps with spike capture + fused conv+linear epilogue
      unsigned mA = 0, mB = 0;
      float4 x0 = rp[0 ^ sw];
      float4 x1 = rp[1 ^ sw];
#pragma unroll
      for (int q = 0; q < 8; ++q) {
        float4 xn = x1;
        if (q + 2 < 8) xn = rp[(q + 2) ^ sw];
        float xs[4] = {x0.x, x0.y, x0.z, x0.w};
#pragma unroll
        for (int r = 0; r < 4; ++r) {
          bool s;
          v = lif_step(xs[r], v, k, vt, s);
          unsigned long long ub = __ballot(s);
          const int t = q * 4 + r;  // compile-time after unroll
          if (tt == t) {
            mA = (unsigned)(ub & 0xffffffffull);
            mB = (unsigned)(ub >> 32);
          }
        }
        x0 = x1; x1 = xn;
      }
      const int ow = w - WWIN;
      outA[ow * 32 + tt] = lut_sum(mA, lut, o, bias);
      outB[ow * 32 + tt] = lut_sum(mB, lut, o, bias);
    }

    if (haveNext) {
      // compiler places the vmcnt wait here -> a full sim window of latency cover
      const int nb = (w + 1) & 1;
      *(lp[0] + nb * BUF4) = s0;
      *(lp[1] + nb * BUF4) = s1;
      *(lp[2] + nb * BUF4) = s2;
    }
  }
}

extern "C" void kernel_launch(void* const* d_in, const int* in_sizes, int n_in,
                              void* d_out, int out_size, void* d_ws, size_t ws_size,
                              hipStream_t stream) {
  const float* x     = (const float*)d_in[0];
  const float* tau   = (const float*)d_in[1];
  const float* vthp  = (const float*)d_in[2];
  const float* convw = (const float*)d_in[3];
  const float* convb = (const float*)d_in[4];
  const float* linw  = (const float*)d_in[5];
  const float* linb  = (const float*)d_in[6];
  float* out = (float*)d_out;

  const int B = in_sizes[0] / (NF * T_LEN);  // 256
  lif_chunked<<<dim3(B, NCHUNKS / 2), dim3(64), 0, stream>>>(
      x, tau, vthp, convw, convb, linw, linb, out);
}

// Round 3
// 148.608 us; speedup vs baseline: 1.0616x; 1.0110x over previous
//
#include <hip/hip_runtime.h>

// Network_49873160241834: fused LIF scan (B=256,F=10,C=3,T=8192) + conv(c) + linear(f).
//
// Speculative time-chunking: LIF resets v to EXACTLY 0 on every spike, and state
// error contracts by (1-k)<=0.8 per step, so a chunk warmed up from v=0 reaches the
// bit-exact true state with overwhelming probability (0.8^128 ~ 4e-13 << ulp, plus
// exact-0 spike sync ~every 2 steps; bench verifies).
//
// ROUND 2 change (resubmitted round 3 -- round 2 bench died on container acquire,
// kernel never ran): occupancy was GRID-limited at 2 waves/SIMD (2048 one-wave
// blocks); VALUBusy ~36% showed SIMDs idle ~2/3 of cycles on the serial v-chain
// latency with nothing to fill the bubbles. WARM 256->128, CHUNK 512->256: 32
// chunks x 384 steps = SAME total step count, but grid (B,16) = 4096 blocks =
// 4 waves/SIMD -> latency hiding doubles at zero extra issue work.
//
// Kept from round 1 (it helped 56->48us): LDS-staged x with T14 async split --
// issue 3 global_load_dwordx4 for window w+1 at loop top, sim window w from LDS
// (~700cyc cover), ds_write at loop bottom; float4-granularity XOR swizzle
// (q ^ (row&7)) on both ds_write and ds_read; per-step x via ds_read_b128 with
// 2-group software prefetch. Each 64-thread block (1 wave, no barriers) simulates
// TWO chunks (half 0 = chunk 2cb, half 1 = chunk 2cb+1).
//
// Spike capture: per step __ballot -> wave-uniform 64-bit mask; lane (o,tt) latches
// it at step tt (cmp + 2 cndmask). Epilogue per 32-step window: 6x(bfe+LDS-LUT+add)
// per chunk-half; LUT[6][2][32] in LDS.
//
// EXACTNESS: v-update uses separately-rounded f32 ops (no FMA contraction) to match
// the f32 reference bit-exactly; chunk-0 staging pointers rewind WARM floats at the
// warmup->main transition to reproduce the original stream.

#define T_LEN 8192
#define NF 10
#define NSEQ 30
#define CHUNK 256
#define WARM 128
#define NCHUNKS 32          // T_LEN / CHUNK
#define NWIN 12             // (WARM + CHUNK) / 32 windows per chunk
#define WWIN 4              // warmup windows
#define NROW 20             // staged rows: 2 halves x 10 f
#define BUF4 (NROW * 8)     // float4s per window buffer (160)

__device__ __forceinline__ float lif_step(float xx, float v, float k, float vt, bool& s) {
  float d  = __fsub_rn(xx, v);   // rounded f32 sub
  float p  = __fmul_rn(k, d);    // rounded f32 mul (NOT fused)
  float vn = __fadd_rn(v, p);    // rounded f32 add
  s = vn > vt;                   // == (fl(vn - vt) > 0) in IEEE f32
  return s ? 0.0f : vn;          // exact reset to +0
}

__device__ __forceinline__ float lut_sum(unsigned m, const float* lut, int o, float bias) {
  float acc = bias;
#pragma unroll
  for (int g = 0; g < 6; ++g) {
    unsigned val = (m >> (5 * g)) & 31u;
    acc += lut[(g * 2 + o) * 32 + val];
  }
  return acc;
}

__global__ __launch_bounds__(64, 4) void lif_chunked(
    const float* __restrict__ x,      // (B, F, T)
    const float* __restrict__ tau,    // (3)
    const float* __restrict__ vth,    // (3)
    const float* __restrict__ convw,  // (3)
    const float* __restrict__ convb,  // (1)
    const float* __restrict__ linw,   // (2,10)
    const float* __restrict__ linb,   // (2)
    float* __restrict__ out)          // (B, 2, T)
{
  const int b    = blockIdx.x;
  const int cb   = blockIdx.y;       // 0..15, handles chunks 2cb, 2cb+1
  const int lane = threadIdx.x;
  const int half = lane >> 5;
  const int j    = lane & 31;
  const bool active = j < NSEQ;
  const int c = active ? j / NF : 0;
  const int f = active ? j % NF : 0;

  // LUT[g][o][val] = sum over set bits p of val of convw[(5g+p)/10]*linw[o,(5g+p)%10]
  __shared__ float lut[384];
  __shared__ float4 xbuf[2][BUF4];   // double-buffered x window, XOR-swizzled
#pragma unroll
  for (int e = 0; e < 6; ++e) {
    int id = lane + 64 * e;
    int g = id >> 6, rem = id & 63, oo = rem >> 5, val = rem & 31;
    float sacc = 0.0f;
#pragma unroll
    for (int p = 0; p < 5; ++p) {
      if (val & (1 << p)) {
        int jj = 5 * g + p;
        sacc += convw[jj / NF] * linw[oo * NF + (jj % NF)];
      }
    }
    lut[id] = sacc;
  }
  __syncthreads();

  const float k  = __fmul_rn(0.001f, tau[c]);
  const float vt = active ? vth[c] : 3.0e38f;   // inactive lanes never spike
  const int chunk = cb * 2 + half;              // this lane's simulated chunk

  // sim-side LDS read base: row = half*10 + f, swizzle key = row & 7
  const int srow = half * NF + f;
  const int sw   = srow & 7;
  const float4* rbase = &xbuf[0][srow * 8];

  // staging assignment: 160 (row,q) float4 slots; slots 0..63 -> lanes (i=0),
  // 64..127 (i=1), 128..159 mirrored on both half-waves (i=2).
  const float4* gp[3];   // global src, advances 8 float4/window
  float4*       lp[3];   // LDS dst in xbuf[0] (+BUF4 for buf 1), swizzled
  int           adj[3];  // chunk-0 rewind (float4 units) at warmup->main
#pragma unroll
  for (int i = 0; i < 3; ++i) {
    int id  = (i == 0) ? lane : (i == 1) ? (lane + 64) : ((lane & 31) + 128);
    int row = id >> 3;
    int q   = id & 7;
    int h   = row / NF;
    int fr  = row % NF;
    int ch  = 2 * cb + h;
    int ts  = (ch == 0) ? 0 : ch * CHUNK - WARM;
    gp[i]  = (const float4*)(x + ((size_t)b * NF + fr) * (size_t)T_LEN + ts) + q;
    lp[i]  = &xbuf[0][row * 8 + (q ^ (row & 7))];
    adj[i] = (ch == 0) ? -(WARM / 4) : 0;
  }

  // epilogue role: lane = (o, tt)
  const int o  = half;
  const int tt = j;
  float wsum = 0.0f;
#pragma unroll
  for (int f2 = 0; f2 < NF; ++f2) wsum += linw[o * NF + f2];
  const float bias = linb[o] + convb[0] * wsum;

  const int tA = 2 * cb * CHUNK;             // half-0 chunk base time (block-uniform)
  float* outA = out + ((size_t)b * 2 + o) * T_LEN + tA;
  float* outB = outA + CHUNK;                // half-1 chunk base

  // ---- prologue: stage window 0 into buf 0
  {
    float4 s0 = gp[0][0], s1 = gp[1][0], s2 = gp[2][0];
    *lp[0] = s0; *lp[1] = s1; *lp[2] = s2;
    gp[0] += 8; gp[1] += 8; gp[2] += 8;
  }

  float v = 0.0f;

#pragma unroll 1
  for (int w = 0; w < NWIN; ++w) {
    const bool haveNext = (w + 1 < NWIN);
    float4 s0, s1, s2;
    if (haveNext) {
      if (w + 1 == WWIN) {   // chunk-0 rows rewind to t=0 for the main phase
        gp[0] += adj[0]; gp[1] += adj[1]; gp[2] += adj[2];
      }
      s0 = gp[0][0]; s1 = gp[1][0]; s2 = gp[2][0];   // issue early (T14)
      gp[0] += 8; gp[1] += 8; gp[2] += 8;
    }

    const float4* rp = rbase + (w & 1) * BUF4;

    if (w < WWIN) {
      // ---- warmup window: 32 steps, no capture
      float4 x0 = rp[0 ^ sw];
      float4 x1 = rp[1 ^ sw];
#pragma unroll
      for (int q = 0; q < 8; ++q) {
        float4 xn = x1;
        if (q + 2 < 8) xn = rp[(q + 2) ^ sw];
        bool s;
        v = lif_step(x0.x, v, k, vt, s);
        v = lif_step(x0.y, v, k, vt, s);
        v = lif_step(x0.z, v, k, vt, s);
        v = lif_step(x0.w, v, k, vt, s);
        x0 = x1; x1 = xn;
      }
      if (w == WWIN - 1) v = (chunk == 0) ? 0.0f : v;  // chunk 0's true init state
    } else {
      // ---- main window: 32 steps with spike capture + fused conv+linear epilogue
      unsigned mA = 0, mB = 0;
      float4 x0 = rp[0 ^ sw];
      float4 x1 = rp[1 ^ sw];
#pragma unroll
      for (int q = 0; q < 8; ++q) {
        float4 xn = x1;
        if (q + 2 < 8) xn = rp[(q + 2) ^ sw];
        float xs[4] = {x0.x, x0.y, x0.z, x0.w};
#pragma unroll
        for (int r = 0; r < 4; ++r) {
          bool s;
          v = lif_step(xs[r], v, k, vt, s);
          unsigned long long ub = __ballot(s);
          const int t = q * 4 + r;  // compile-time after unroll
          if (tt == t) {
            mA = (unsigned)(ub & 0xffffffffull);
            mB = (unsigned)(ub >> 32);
          }
        }
        x0 = x1; x1 = xn;
      }
      const int ow = w - WWIN;
      outA[ow * 32 + tt] = lut_sum(mA, lut, o, bias);
      outB[ow * 32 + tt] = lut_sum(mB, lut, o, bias);
    }

    if (haveNext) {
      // compiler places the vmcnt wait here -> a full sim window of latency cover
      const int nb = (w + 1) & 1;
      *(lp[0] + nb * BUF4) = s0;
      *(lp[1] + nb * BUF4) = s1;
      *(lp[2] + nb * BUF4) = s2;
    }
  }
}

extern "C" void kernel_launch(void* const* d_in, const int* in_sizes, int n_in,
                              void* d_out, int out_size, void* d_ws, size_t ws_size,
                              hipStream_t stream) {
  const float* x     = (const float*)d_in[0];
  const float* tau   = (const float*)d_in[1];
  const float* vthp  = (const float*)d_in[2];
  const float* convw = (const float*)d_in[3];
  const float* convb = (const float*)d_in[4];
  const float* linw  = (const float*)d_in[5];
  const float* linb  = (const float*)d_in[6];
  float* out = (float*)d_out;

  const int B = in_sizes[0] / (NF * T_LEN);  // 256
  lif_chunked<<<dim3(B, NCHUNKS / 2), dim3(64), 0, stream>>>(
      x, tau, vthp, convw, convb, linw, linb, out);
}